// Round 19
// baseline (1327.740 us; speedup 1.0000x reference)
//
#include <hip/hip_runtime.h>

// LIF layer: B=64, T=256, P=1024, D=1024. reference ignores prv_voltage.
// d_out = [voltage (B*T*D fp32) | spikes (B*T*D fp32)].
//
// NUMERICS LOCKED (R10): currents[row,d] =
//   (asc-p f32 single-acc sum over active p in [0,512))
// + (asc-p f32 single-acc sum over active p in [512,1024)), f32;
// scan = f32 separate mul-then-add, >=1.0, reset-to-zero.
//
// R19: ROW-BATCHING to cut the 6.7GB W-gather (the measured limiter: ~24TB/s
// L2 rate across R10-R18; MLP/nt/LDS variants all plateaued). Block = 8 rows
// x 4 waves(256 cols each). Per 64-p chunk: union mask of the 8 rows (~57%
// density at R=8 -> traffic x0.70); walk union ascending; load W slice ONCE;
// add into each active row via WAVE-UNIFORM scalar branch (masks are
// readfirstlane'd -> s_and+s_cbranch, no divergence, no cndmask = avoids
// R11's failure). Per-row ascending order preserved; chunks 0-7 -> accA,
// 8-15 -> accB; accA+accB final = locked panel association. 2-deep load
// pipeline for MLP. All nt hints dropped (R16-R18: net negative on total).

#define LIF_B 64
#define LIF_T 256
#define LIF_P 1024
#define LIF_D 1024
#define LIF_N ((size_t)LIF_B * LIF_T * LIF_D)

__device__ __forceinline__ unsigned long long rfl64(unsigned long long x) {
    return ((unsigned long long)__builtin_amdgcn_readfirstlane((unsigned)(x >> 32)) << 32)
         | (unsigned)__builtin_amdgcn_readfirstlane((unsigned)x);
}

__global__ __launch_bounds__(256) void lif_currents_kernel(
    const float* __restrict__ spikes,   // (B*T, P)
    const float* __restrict__ W,        // (P, D)
    float* __restrict__ cur_out)        // (B*T, D) — voltage region of d_out
{
    __shared__ unsigned long long masks[8][16];   // 1 KB

    const int tid  = threadIdx.x;
    const int lane = tid & 63;
    const int wave = tid >> 6;            // 4 waves x 256 d-columns
    const int row0 = blockIdx.x << 3;     // 8 rows per block
    const int dbase = wave << 8;

    const float* wcol = W + dbase + (lane << 2);   // this lane's 4 columns

    // Phase 1: masks for 8 rows x 16 chunks; wave w handles rows 2w, 2w+1.
    for (int k = 0; k < 2; ++k) {
        const int r = (wave << 1) | k;
        const float* srow = spikes + (size_t)(row0 + r) * LIF_P;
        #pragma unroll 4
        for (int c = 0; c < 16; ++c) {
            const float sv = srow[(c << 6) + lane];
            const unsigned long long m = __ballot(sv != 0.0f);
            if (lane == 0) masks[r][c] = m;
        }
    }
    __syncthreads();

    float4 aA0{0,0,0,0}, aA1{0,0,0,0}, aA2{0,0,0,0}, aA3{0,0,0,0};
    float4 aA4{0,0,0,0}, aA5{0,0,0,0}, aA6{0,0,0,0}, aA7{0,0,0,0};
    float4 aB0{0,0,0,0}, aB1{0,0,0,0}, aB2{0,0,0,0}, aB3{0,0,0,0};
    float4 aB4{0,0,0,0}, aB5{0,0,0,0}, aB6{0,0,0,0}, aB7{0,0,0,0};

    #define LIF_ACC4(A, WV)                                                   \
        (A).x = __fadd_rn((A).x, (WV).x); (A).y = __fadd_rn((A).y, (WV).y);   \
        (A).z = __fadd_rn((A).z, (WV).z); (A).w = __fadd_rn((A).w, (WV).w);

    // add wv into each row whose (scalar) mask has bit p — wave-uniform tests
    #define LIF_PROC(P, WV, A0,A1,A2,A3,A4,A5,A6,A7)                          \
    {                                                                         \
        const unsigned long long bit = 1ull << (P);                           \
        if (m0 & bit) { LIF_ACC4(A0, WV) }                                    \
        if (m1 & bit) { LIF_ACC4(A1, WV) }                                    \
        if (m2 & bit) { LIF_ACC4(A2, WV) }                                    \
        if (m3 & bit) { LIF_ACC4(A3, WV) }                                    \
        if (m4 & bit) { LIF_ACC4(A4, WV) }                                    \
        if (m5 & bit) { LIF_ACC4(A5, WV) }                                    \
        if (m6 & bit) { LIF_ACC4(A6, WV) }                                    \
        if (m7 & bit) { LIF_ACC4(A7, WV) }                                    \
    }

    // one 64-p chunk: union walk, ascending, 2-deep load pipeline
    #define LIF_CHUNK(C, A0,A1,A2,A3,A4,A5,A6,A7)                             \
    {                                                                         \
        const unsigned long long m0 = rfl64(masks[0][(C)]);                   \
        const unsigned long long m1 = rfl64(masks[1][(C)]);                   \
        const unsigned long long m2 = rfl64(masks[2][(C)]);                   \
        const unsigned long long m3 = rfl64(masks[3][(C)]);                   \
        const unsigned long long m4 = rfl64(masks[4][(C)]);                   \
        const unsigned long long m5 = rfl64(masks[5][(C)]);                   \
        const unsigned long long m6 = rfl64(masks[6][(C)]);                   \
        const unsigned long long m7 = rfl64(masks[7][(C)]);                   \
        unsigned long long u = (m0|m1)|(m2|m3)|((m4|m5)|(m6|m7));             \
        const float* wb = wcol + ((size_t)(C) << 16);                         \
        if (u) {                                                              \
            int p = __builtin_ctzll(u); u &= (u - 1);                         \
            float4 wv = *reinterpret_cast<const float4*>(wb + ((size_t)p << 10)); \
            while (u) {                                                       \
                const int pn = __builtin_ctzll(u); u &= (u - 1);              \
                const float4 wn = *reinterpret_cast<const float4*>(wb + ((size_t)pn << 10)); \
                LIF_PROC(p, wv, A0,A1,A2,A3,A4,A5,A6,A7)                      \
                p = pn; wv = wn;                                              \
            }                                                                 \
            LIF_PROC(p, wv, A0,A1,A2,A3,A4,A5,A6,A7)                          \
        }                                                                     \
    }

    // panel 0: chunks 0..7 (p in [0,512)) -> accA
    #pragma unroll 1
    for (int c = 0; c < 8; ++c)  { LIF_CHUNK(c, aA0,aA1,aA2,aA3,aA4,aA5,aA6,aA7) }
    // panel 1: chunks 8..15 (p in [512,1024)) -> accB
    #pragma unroll 1
    for (int c = 8; c < 16; ++c) { LIF_CHUNK(c, aB0,aB1,aB2,aB3,aB4,aB5,aB6,aB7) }

    #undef LIF_CHUNK
    #undef LIF_PROC
    #undef LIF_ACC4

    // epilogue: locked panel association P0 + P1, store 8 rows
    #define LIF_STORE(R, A, Bv)                                               \
    {                                                                         \
        float4 c4;                                                            \
        c4.x = __fadd_rn((A).x, (Bv).x);                                      \
        c4.y = __fadd_rn((A).y, (Bv).y);                                      \
        c4.z = __fadd_rn((A).z, (Bv).z);                                      \
        c4.w = __fadd_rn((A).w, (Bv).w);                                      \
        *reinterpret_cast<float4*>(cur_out + (size_t)(row0 + (R)) * LIF_D     \
                                   + dbase + (lane << 2)) = c4;               \
    }
    LIF_STORE(0, aA0, aB0) LIF_STORE(1, aA1, aB1)
    LIF_STORE(2, aA2, aB2) LIF_STORE(3, aA3, aB3)
    LIF_STORE(4, aA4, aB4) LIF_STORE(5, aA5, aB5)
    LIF_STORE(6, aA6, aB6) LIF_STORE(7, aA7, aB7)
    #undef LIF_STORE
}

__global__ __launch_bounds__(256) void lif_scan_kernel(
    float* __restrict__ voltage,        // in: staged currents, out: v_new
    float* __restrict__ spikes_out)     // out: binary spikes
{
    const int tid = blockIdx.x * 256 + threadIdx.x;   // 0 .. B*D-1
    const int b = tid >> 10;
    const int d = tid & (LIF_D - 1);

    float v = 0.0f;
    const size_t base = ((size_t)b * LIF_T) * LIF_D + d;

    // 4-deep prefetch: current loads don't depend on the serial v chain.
    float p0 = voltage[base + 0*(size_t)LIF_D];
    float p1 = voltage[base + 1*(size_t)LIF_D];
    float p2 = voltage[base + 2*(size_t)LIF_D];
    float p3 = voltage[base + 3*(size_t)LIF_D];

    for (int t = 0; t < LIF_T; t += 4) {
        const float c0 = p0, c1 = p1, c2 = p2, c3 = p3;
        if (t + 4 < LIF_T) {
            p0 = voltage[base + (size_t)(t + 4) * LIF_D];
            p1 = voltage[base + (size_t)(t + 5) * LIF_D];
            p2 = voltage[base + (size_t)(t + 6) * LIF_D];
            p3 = voltage[base + (size_t)(t + 7) * LIF_D];
        }
        const size_t i0 = base + (size_t)t * LIF_D;
        // numpy scan: separate f32 mul then add (no FMA contraction) — locked.
        {
            const float vn = __fadd_rn(__fmul_rn(0.9f, v), c0);
            const bool f = (vn >= 1.0f);
            voltage[i0 + 0*(size_t)LIF_D] = vn;
            spikes_out[i0 + 0*(size_t)LIF_D] = f ? 1.0f : 0.0f;
            v = f ? 0.0f : vn;
        }
        {
            const float vn = __fadd_rn(__fmul_rn(0.9f, v), c1);
            const bool f = (vn >= 1.0f);
            voltage[i0 + 1*(size_t)LIF_D] = vn;
            spikes_out[i0 + 1*(size_t)LIF_D] = f ? 1.0f : 0.0f;
            v = f ? 0.0f : vn;
        }
        {
            const float vn = __fadd_rn(__fmul_rn(0.9f, v), c2);
            const bool f = (vn >= 1.0f);
            voltage[i0 + 2*(size_t)LIF_D] = vn;
            spikes_out[i0 + 2*(size_t)LIF_D] = f ? 1.0f : 0.0f;
            v = f ? 0.0f : vn;
        }
        {
            const float vn = __fadd_rn(__fmul_rn(0.9f, v), c3);
            const bool f = (vn >= 1.0f);
            voltage[i0 + 3*(size_t)LIF_D] = vn;
            spikes_out[i0 + 3*(size_t)LIF_D] = f ? 1.0f : 0.0f;
            v = f ? 0.0f : vn;
        }
    }
}

extern "C" void kernel_launch(void* const* d_in, const int* in_sizes, int n_in,
                              void* d_out, int out_size, void* d_ws, size_t ws_size,
                              hipStream_t stream) {
    (void)in_sizes; (void)n_in; (void)out_size; (void)d_ws; (void)ws_size;

    // d_in[0] = prv_voltage (UNUSED by reference)
    const float* spikes = (const float*)d_in[1];   // (B,T,P) binary fp32
    const float* W      = (const float*)d_in[2];   // (P,D) fp32

    float* out        = (float*)d_out;
    float* voltage    = out;                       // N floats (stages currents)
    float* spikes_out = out + LIF_N;               // N floats

    lif_currents_kernel<<<(LIF_B * LIF_T) / 8, 256, 0, stream>>>(spikes, W, voltage);
    lif_scan_kernel<<<(LIF_B * LIF_D) / 256, 256, 0, stream>>>(voltage, spikes_out);
}

// Round 20
// 272.208 us; speedup vs baseline: 4.8777x; 4.8777x over previous
//
#include <hip/hip_runtime.h>

// LIF layer: B=64, T=256, P=1024, D=1024. reference ignores prv_voltage.
// d_out = [voltage (B*T*D fp32) | spikes (B*T*D fp32)].
//
// NUMERICS LOCKED (R10 passed): currents[row,d] =
//   (asc-p f32 single-acc sum over active p in [0,512))
// + (asc-p f32 single-acc sum over active p in [512,1024)), f32;
// scan = f32 separate mul-then-add, >=1.0, reset-to-zero.
//
// R20 = R12 VERBATIM (empirical best: 272us total). Exploration summary:
//   R11 8-wide cndmask batch: VALU 2x + dup loads -> 397us  [refuted]
//   R13/R14 LDS staging (serial / double-buffered): 433/477us [refuted]
//   R16-R18 nt-hint variants: FETCH halves but total 291-308  [refuted]
//   R18 8-wide plist walk: ==R12 within noise                 [no gain]
//   R19 8-row union batching: FETCH -30% but branch-bound 5x  [refuted]
// R12's K1 runs the 6.7GB W-gather at ~24TB/s = the measured L2 ceiling for
// 1KB-granular gathers (70% of the 34.5TB/s streaming ubench; remainder is
// sector/channel granularity). K2 is at its ~32us HBM floor. MFMA is
// numerically forbidden (locked sum order; knife-edge dataset).

#define LIF_B 64
#define LIF_T 256
#define LIF_P 1024
#define LIF_D 1024
#define LIF_N ((size_t)LIF_B * LIF_T * LIF_D)

__global__ __launch_bounds__(256) void lif_currents_kernel(
    const float* __restrict__ spikes,   // (B*T, P)
    const float* __restrict__ W,        // (P, D)
    float* __restrict__ cur_out)        // (B*T, D) — voltage region of d_out
{
    __shared__ unsigned long long smask[16];
    __shared__ int plist[1024];          // panel0 at [0..c0), panel1 at [512..512+c1)
    __shared__ int scnt[2];

    const int row  = blockIdx.x;          // 0 .. B*T-1
    const int tid  = threadIdx.x;
    const int lane = tid & 63;
    const int wave = tid >> 6;            // 4 waves x 256 d-columns
    const int dbase = wave << 8;

    const float* srow = spikes + (size_t)row * LIF_P;
    const float* wcol = W + dbase + (lane << 2);   // this lane's 4 columns

    // Phase 1: cooperative mask build — wave w handles chunks 4w..4w+3.
    for (int jj = 0; jj < 4; ++jj) {
        const int j = (wave << 2) + jj;
        const float sv = srow[(j << 6) + lane];
        const unsigned long long m = __ballot(sv != 0.0f);
        if (lane == 0) smask[j] = m;
    }
    __syncthreads();

    // Phase 2: wave 0, lanes 0..15 build ascending p-lists (one chunk each).
    if (wave == 0) {
        unsigned long long m = (lane < 16) ? smask[lane] : 0ULL;
        const int pc = __popcll(m);
        int s = pc;                       // inclusive prefix within 8-lane group
        for (int d = 1; d < 8; d <<= 1) {
            const int vps = __shfl_up(s, d, 8);
            if ((lane & 7) >= d) s += vps;
        }
        if (lane == 7)  scnt[0] = s;
        if (lane == 15) scnt[1] = s;
        if (lane < 16) {
            int idx = ((lane < 8) ? 0 : 512) + (s - pc);
            const int pb = lane << 6;
            while (m) {
                plist[idx++] = pb + __builtin_ctzll(m);
                m &= (m - 1);
            }
        }
    }
    __syncthreads();

    const int c0 = scnt[0];
    const int c1 = scnt[1];

    float a0x=0.f,a0y=0.f,a0z=0.f,a0w=0.f;
    float a1x=0.f,a1y=0.f,a1z=0.f,a1w=0.f;

    #define LIF_ACC(AX,AY,AZ,AW,WV)                                             \
        AX = __fadd_rn(AX, (WV).x); AY = __fadd_rn(AY, (WV).y);                  \
        AZ = __fadd_rn(AZ, (WV).z); AW = __fadd_rn(AW, (WV).w);

    #define LIF_PANEL(BASE, CNT, AX,AY,AZ,AW)                                    \
    {                                                                            \
        int i = 0;                                                               \
        for (; i + 4 <= (CNT); i += 4) {                                         \
            const int4 ps = *reinterpret_cast<const int4*>(&plist[(BASE) + i]);  \
            const float4 w0 = *reinterpret_cast<const float4*>(wcol + ((size_t)ps.x << 10)); \
            const float4 w1 = *reinterpret_cast<const float4*>(wcol + ((size_t)ps.y << 10)); \
            const float4 w2 = *reinterpret_cast<const float4*>(wcol + ((size_t)ps.z << 10)); \
            const float4 w3 = *reinterpret_cast<const float4*>(wcol + ((size_t)ps.w << 10)); \
            LIF_ACC(AX,AY,AZ,AW, w0) LIF_ACC(AX,AY,AZ,AW, w1)                    \
            LIF_ACC(AX,AY,AZ,AW, w2) LIF_ACC(AX,AY,AZ,AW, w3)                    \
        }                                                                        \
        for (; i < (CNT); ++i) {                                                 \
            const int p = plist[(BASE) + i];                                     \
            const float4 wv = *reinterpret_cast<const float4*>(wcol + ((size_t)p << 10)); \
            LIF_ACC(AX,AY,AZ,AW, wv)                                             \
        }                                                                        \
    }

    LIF_PANEL(0,   c0, a0x,a0y,a0z,a0w)   // p in [0, 512), ascending
    LIF_PANEL(512, c1, a1x,a1y,a1z,a1w)   // p in [512, 1024), ascending
    #undef LIF_PANEL
    #undef LIF_ACC

    // Panel association: P0 + P1, plain f32 add (locked).
    float4 c;
    c.x = __fadd_rn(a0x, a1x);
    c.y = __fadd_rn(a0y, a1y);
    c.z = __fadd_rn(a0z, a1z);
    c.w = __fadd_rn(a0w, a1w);

    *reinterpret_cast<float4*>(cur_out + (size_t)row * LIF_D + dbase + (lane << 2)) = c;
}

__global__ __launch_bounds__(256) void lif_scan_kernel(
    float* __restrict__ voltage,        // in: staged currents, out: v_new
    float* __restrict__ spikes_out)     // out: binary spikes
{
    const int tid = blockIdx.x * 256 + threadIdx.x;   // 0 .. B*D-1
    const int b = tid >> 10;
    const int d = tid & (LIF_D - 1);

    float v = 0.0f;
    const size_t base = ((size_t)b * LIF_T) * LIF_D + d;

    // 4-deep prefetch: current loads don't depend on the serial v chain.
    float p0 = voltage[base + 0*(size_t)LIF_D];
    float p1 = voltage[base + 1*(size_t)LIF_D];
    float p2 = voltage[base + 2*(size_t)LIF_D];
    float p3 = voltage[base + 3*(size_t)LIF_D];

    for (int t = 0; t < LIF_T; t += 4) {
        const float c0 = p0, c1 = p1, c2 = p2, c3 = p3;
        if (t + 4 < LIF_T) {
            p0 = voltage[base + (size_t)(t + 4) * LIF_D];
            p1 = voltage[base + (size_t)(t + 5) * LIF_D];
            p2 = voltage[base + (size_t)(t + 6) * LIF_D];
            p3 = voltage[base + (size_t)(t + 7) * LIF_D];
        }
        const size_t i0 = base + (size_t)t * LIF_D;
        // numpy scan: separate f32 mul then add (no FMA contraction) — locked.
        {
            const float vn = __fadd_rn(__fmul_rn(0.9f, v), c0);
            const bool f = (vn >= 1.0f);
            voltage[i0 + 0*(size_t)LIF_D] = vn;
            spikes_out[i0 + 0*(size_t)LIF_D] = f ? 1.0f : 0.0f;
            v = f ? 0.0f : vn;
        }
        {
            const float vn = __fadd_rn(__fmul_rn(0.9f, v), c1);
            const bool f = (vn >= 1.0f);
            voltage[i0 + 1*(size_t)LIF_D] = vn;
            spikes_out[i0 + 1*(size_t)LIF_D] = f ? 1.0f : 0.0f;
            v = f ? 0.0f : vn;
        }
        {
            const float vn = __fadd_rn(__fmul_rn(0.9f, v), c2);
            const bool f = (vn >= 1.0f);
            voltage[i0 + 2*(size_t)LIF_D] = vn;
            spikes_out[i0 + 2*(size_t)LIF_D] = f ? 1.0f : 0.0f;
            v = f ? 0.0f : vn;
        }
        {
            const float vn = __fadd_rn(__fmul_rn(0.9f, v), c3);
            const bool f = (vn >= 1.0f);
            voltage[i0 + 3*(size_t)LIF_D] = vn;
            spikes_out[i0 + 3*(size_t)LIF_D] = f ? 1.0f : 0.0f;
            v = f ? 0.0f : vn;
        }
    }
}

extern "C" void kernel_launch(void* const* d_in, const int* in_sizes, int n_in,
                              void* d_out, int out_size, void* d_ws, size_t ws_size,
                              hipStream_t stream) {
    (void)in_sizes; (void)n_in; (void)out_size; (void)d_ws; (void)ws_size;

    // d_in[0] = prv_voltage (UNUSED by reference)
    const float* spikes = (const float*)d_in[1];   // (B,T,P) binary fp32
    const float* W      = (const float*)d_in[2];   // (P,D) fp32

    float* out        = (float*)d_out;
    float* voltage    = out;                       // N floats (stages currents)
    float* spikes_out = out + LIF_N;               // N floats

    lif_currents_kernel<<<LIF_B * LIF_T, 256, 0, stream>>>(spikes, W, voltage);
    lif_scan_kernel<<<(LIF_B * LIF_D) / 256, 256, 0, stream>>>(voltage, spikes_out);
}